// Round 1
// baseline (1589.663 us; speedup 1.0000x reference)
//
#include <hip/hip_runtime.h>

// Problem constants (from reference)
constexpr int D_IN  = 64;
constexpr int D_H1  = 32;
constexpr int D_H2  = 64;
constexpr int D_OUT = 128;
constexpr int NSEG  = 8192;

constexpr int CHUNK = 512;  // rows per block
constexpr int TILE  = 32;   // rows per LDS tile
constexpr int BLOCK = 128;  // one thread per output feature

__global__ __launch_bounds__(BLOCK) void mlp_seg_kernel(
    const float* __restrict__ f, const int* __restrict__ seg,
    const float* __restrict__ W1, const float* __restrict__ b1,
    const float* __restrict__ W2, const float* __restrict__ b2,
    const float* __restrict__ W3, const float* __restrict__ b3,
    float* __restrict__ sums, float* __restrict__ counts, int N)
{
    __shared__ __align__(16) float sW1[D_IN * D_H1];   // 8 KB
    __shared__ __align__(16) float sW2[D_H1 * D_H2];   // 8 KB
    __shared__ float sb1[D_H1];
    __shared__ float sb2[D_H2];
    __shared__ __align__(16) float sf [TILE * D_IN];   // 8 KB
    __shared__ __align__(16) float sh1[TILE * D_H1];   // 4 KB
    __shared__ __align__(16) float sh2[TILE * D_H2];   // 8 KB
    __shared__ int sseg[TILE];

    const int tid = threadIdx.x;   // 0..127 = output feature owned

    // Stage W1/W2/biases into LDS (once per block)
    for (int i = tid; i < D_IN * D_H1; i += BLOCK) sW1[i] = W1[i];
    for (int i = tid; i < D_H1 * D_H2; i += BLOCK) sW2[i] = W2[i];
    if (tid < D_H1) sb1[tid] = b1[tid];
    if (tid < D_H2) sb2[tid] = b2[tid];

    // W3 column for my feature -> registers (coalesced across lanes per k)
    float w3c[D_H2];
    #pragma unroll
    for (int k = 0; k < D_H2; ++k) w3c[k] = W3[k * D_OUT + tid];
    const float b3r = b3[tid];

    const int row0   = blockIdx.x * CHUNK;
    const int rowEnd = min(row0 + CHUNK, N);

    float run_sum = 0.f;   // running segment sum for my feature
    int   cur_seg = -1;    // uniform across block (rows processed in lockstep)
    int   run_len = 0;

    __syncthreads();

    for (int t0 = row0; t0 < rowEnd; t0 += TILE) {
        const int nrows = min(TILE, rowEnd - t0);

        // ---- stage f tile (row-major contiguous, float4 coalesced) ----
        const int nf4 = nrows * D_IN / 4;   // D_IN=64 -> always multiple of 4
        const float4* gsrc = (const float4*)(f + (size_t)t0 * D_IN);
        for (int i = tid; i < nf4; i += BLOCK) ((float4*)sf)[i] = gsrc[i];
        if (tid < nrows) sseg[tid] = seg[t0 + tid];
        __syncthreads();

        // ---- layer 1: h1[r][j] = relu(f[r]·W1[:,j] + b1[j]) ----
        for (int e = tid; e < nrows * D_H1; e += BLOCK) {
            const int r = e >> 5, j = e & 31;
            float a0 = 0.f, a1 = 0.f, a2 = 0.f, a3 = 0.f;
            #pragma unroll
            for (int k = 0; k < D_IN; k += 4) {
                a0 += sf[r * D_IN + k + 0] * sW1[(k + 0) * D_H1 + j];
                a1 += sf[r * D_IN + k + 1] * sW1[(k + 1) * D_H1 + j];
                a2 += sf[r * D_IN + k + 2] * sW1[(k + 2) * D_H1 + j];
                a3 += sf[r * D_IN + k + 3] * sW1[(k + 3) * D_H1 + j];
            }
            const float acc = sb1[j] + ((a0 + a1) + (a2 + a3));
            sh1[e] = fmaxf(acc, 0.f);
        }
        __syncthreads();

        // ---- layer 2: h2[r][j] = relu(h1[r]·W2[:,j] + b2[j]) ----
        for (int e = tid; e < nrows * D_H2; e += BLOCK) {
            const int r = e >> 6, j = e & 63;
            float a0 = 0.f, a1 = 0.f, a2 = 0.f, a3 = 0.f;
            #pragma unroll
            for (int k = 0; k < D_H1; k += 4) {
                a0 += sh1[r * D_H1 + k + 0] * sW2[(k + 0) * D_H2 + j];
                a1 += sh1[r * D_H1 + k + 1] * sW2[(k + 1) * D_H2 + j];
                a2 += sh1[r * D_H1 + k + 2] * sW2[(k + 2) * D_H2 + j];
                a3 += sh1[r * D_H1 + k + 3] * sW2[(k + 3) * D_H2 + j];
            }
            const float acc = sb2[j] + ((a0 + a1) + (a2 + a3));
            sh2[e] = fmaxf(acc, 0.f);
        }
        __syncthreads();

        // ---- layer 3 + segment-run accumulation (rows in lockstep) ----
        for (int r = 0; r < nrows; ++r) {
            const int s = sseg[r];
            if (s != cur_seg) {                      // uniform branch
                if (cur_seg >= 0) {
                    atomicAdd(&sums[(size_t)cur_seg * D_OUT + tid], run_sum);
                    if (tid == 0) atomicAdd(&counts[cur_seg], (float)run_len);
                }
                cur_seg = s; run_sum = 0.f; run_len = 0;
            }
            float a0 = 0.f, a1 = 0.f, a2 = 0.f, a3 = 0.f;
            #pragma unroll
            for (int k = 0; k < D_H2; k += 4) {      // sh2[r][*] broadcast reads
                a0 += sh2[r * D_H2 + k + 0] * w3c[k + 0];
                a1 += sh2[r * D_H2 + k + 1] * w3c[k + 1];
                a2 += sh2[r * D_H2 + k + 2] * w3c[k + 2];
                a3 += sh2[r * D_H2 + k + 3] * w3c[k + 3];
            }
            run_sum += b3r + ((a0 + a1) + (a2 + a3));
            run_len++;
        }
        __syncthreads();   // protect sf/sh1/sh2 reuse next tile
    }

    if (cur_seg >= 0) {
        atomicAdd(&sums[(size_t)cur_seg * D_OUT + tid], run_sum);
        if (tid == 0) atomicAdd(&counts[cur_seg], (float)run_len);
    }
}

__global__ __launch_bounds__(256) void div_kernel(
    const float* __restrict__ sums, const float* __restrict__ counts,
    float* __restrict__ out, int total)
{
    const int i = blockIdx.x * 256 + threadIdx.x;
    if (i < total) {
        out[i] = sums[i] / fmaxf(counts[i >> 7], 1.f);
    }
}

extern "C" void kernel_launch(void* const* d_in, const int* in_sizes, int n_in,
                              void* d_out, int out_size, void* d_ws, size_t ws_size,
                              hipStream_t stream) {
    const float* f   = (const float*)d_in[0];
    const int*   seg = (const int*)  d_in[1];
    // d_in[2] = num_segments scalar (known: 8192)
    const float* W1 = (const float*)d_in[3];
    const float* b1 = (const float*)d_in[4];
    const float* W2 = (const float*)d_in[5];
    const float* b2 = (const float*)d_in[6];
    const float* W3 = (const float*)d_in[7];
    const float* b3 = (const float*)d_in[8];
    float* out = (float*)d_out;

    const int N = in_sizes[0] / D_IN;

    float* sums   = (float*)d_ws;                       // [NSEG * D_OUT]
    float* counts = sums + (size_t)NSEG * D_OUT;        // [NSEG]

    hipMemsetAsync(d_ws, 0, ((size_t)NSEG * D_OUT + NSEG) * sizeof(float), stream);

    const int nblocks = (N + CHUNK - 1) / CHUNK;
    mlp_seg_kernel<<<nblocks, BLOCK, 0, stream>>>(f, seg, W1, b1, W2, b2, W3, b3,
                                                  sums, counts, N);

    const int total = NSEG * D_OUT;
    div_kernel<<<(total + 255) / 256, 256, 0, stream>>>(sums, counts, out, total);
}

// Round 2
// 477.785 us; speedup vs baseline: 3.3272x; 3.3272x over previous
//
#include <hip/hip_runtime.h>

constexpr int D_IN  = 64;
constexpr int D_H1  = 32;
constexpr int D_H2  = 64;
constexpr int D_OUT = 128;
constexpr int NSEG  = 8192;

constexpr int BLOCK = 256;       // 4 waves
constexpr int RT    = 64;        // rows per tile
constexpr int TPB   = 8;        // tiles per block -> 1954 blocks
constexpr int SYS   = D_OUT + 8; // sy row stride (bf16), pad breaks write conflicts

typedef __bf16 bfx8 __attribute__((ext_vector_type(8)));
typedef __bf16 bfx4 __attribute__((ext_vector_type(4)));
typedef float  fx4  __attribute__((ext_vector_type(4)));

// MFMA 16x16x32 bf16 layouts (m89-verified):
//   A: m = lane&15, k = (lane>>4)*8 + j   (8 contiguous k -> ds_read_b128)
//   B: n = lane&15, k = (lane>>4)*8 + i
//   D: row(m) = (lane>>4)*4 + reg, col(n) = lane&15

__global__ __launch_bounds__(BLOCK, 3) void mlp_seg_mfma(
    const float* __restrict__ f, const int* __restrict__ seg,
    const float* __restrict__ W1, const float* __restrict__ b1,
    const float* __restrict__ W2, const float* __restrict__ b2,
    const float* __restrict__ W3, const float* __restrict__ b3,
    float* __restrict__ sums, float* __restrict__ counts,
    int N, int ntiles)
{
    __shared__ __align__(16) __bf16 sf [RT * 64];   // 8 KB  (XOR-swizzled chunks)
    __shared__ __align__(16) __bf16 sh1[RT * 32];   // 4 KB
    __shared__ __align__(16) __bf16 sh2[RT * 64];   // 8 KB
    __shared__ __align__(16) __bf16 sy [RT * SYS];  // 17 KB (padded, unswizzled)
    __shared__ int sseg[RT];

    const int tid  = threadIdx.x;
    const int wv   = tid >> 6;
    const int lane = tid & 63;
    const int lr   = lane & 15;
    const int quad = lane >> 4;
    const int m0   = wv * 16;          // this wave's 16-row slice of the tile
    const int ar   = m0 + lr;          // A-fragment row for this lane

    // ---- weight B-fragments + biases -> registers (one-time, L2-cached) ----
    bfx8 fw1[2][2];                    // [ntile][kstep]  W1[64][32]
    #pragma unroll
    for (int j = 0; j < 2; ++j)
        #pragma unroll
        for (int ks = 0; ks < 2; ++ks)
            #pragma unroll
            for (int i = 0; i < 8; ++i)
                fw1[j][ks][i] = (__bf16)W1[(ks*32 + quad*8 + i)*D_H1 + j*16 + lr];

    bfx8 fw2[4];                       // W2[32][64], K=32 single step
    #pragma unroll
    for (int j = 0; j < 4; ++j)
        #pragma unroll
        for (int i = 0; i < 8; ++i)
            fw2[j][i] = (__bf16)W2[(quad*8 + i)*D_H2 + j*16 + lr];

    bfx8 fw3[8][2];                    // W3[64][128]
    #pragma unroll
    for (int j = 0; j < 8; ++j)
        #pragma unroll
        for (int ks = 0; ks < 2; ++ks)
            #pragma unroll
            for (int i = 0; i < 8; ++i)
                fw3[j][ks][i] = (__bf16)W3[(ks*32 + quad*8 + i)*D_OUT + j*16 + lr];

    float rb1[2], rb2[4], rb3[8];
    #pragma unroll
    for (int j = 0; j < 2; ++j) rb1[j] = b1[j*16 + lr];
    #pragma unroll
    for (int j = 0; j < 4; ++j) rb2[j] = b2[j*16 + lr];
    #pragma unroll
    for (int j = 0; j < 8; ++j) rb3[j] = b3[j*16 + lr];

    // ---- persistent segment-run state (two 128-thread groups) ----
    const int colA = tid & 127;        // owned output column
    const int grp  = tid >> 7;         // group 0: rows 0..31, group 1: rows 32..63
    int   cur_seg = -1;
    float run_sum = 0.f;
    int   run_len = 0;

    const int t0 = blockIdx.x * TPB;
    const int t1 = min(t0 + TPB, ntiles);

    for (int t = t0; t < t1; ++t) {
        const int R0 = t * RT;

        // ---- stage f tile: global float4 (coalesced) -> bf16 -> swizzled LDS ----
        const float4* f4 = (const float4*)f + (size_t)R0 * 16;
        #pragma unroll
        for (int i = 0; i < 4; ++i) {
            const int idx4 = tid + i * 256;
            float4 q = make_float4(0.f, 0.f, 0.f, 0.f);
            if ((size_t)R0 * 64 + (size_t)idx4 * 4 < (size_t)N * 64) q = f4[idx4];
            const int r = idx4 >> 4;
            const int c = (idx4 & 15) * 4;
            bfx4 v;
            v[0] = (__bf16)q.x; v[1] = (__bf16)q.y;
            v[2] = (__bf16)q.z; v[3] = (__bf16)q.w;
            const int pe = r*64 + ((((c >> 3) ^ (r & 7))) << 3) + (c & 7);
            *(bfx4*)&sf[pe] = v;
        }
        if (tid < RT) sseg[tid] = (R0 + tid < N) ? seg[R0 + tid] : -2;
        __syncthreads();

        // ---- L1: [16,64]@[64,32] per wave ----
        fx4 acc1[2] = {{0,0,0,0},{0,0,0,0}};
        #pragma unroll
        for (int ks = 0; ks < 2; ++ks) {
            bfx8 a = *(const bfx8*)&sf[ar*64 + (((ks*4 + quad) ^ (ar & 7)) << 3)];
            #pragma unroll
            for (int j = 0; j < 2; ++j)
                acc1[j] = __builtin_amdgcn_mfma_f32_16x16x32_bf16(a, fw1[j][ks], acc1[j], 0, 0, 0);
        }
        #pragma unroll
        for (int j = 0; j < 2; ++j)
            #pragma unroll
            for (int rg = 0; rg < 4; ++rg) {
                const int row = m0 + quad*4 + rg;
                const int col = j*16 + lr;
                const float v = fmaxf(acc1[j][rg] + rb1[j], 0.f);
                sh1[row*32 + (((col >> 3) ^ (row & 3)) << 3) + (col & 7)] = (__bf16)v;
            }
        // no barrier: sh1 rows [m0, m0+16) are written and read by this wave only

        // ---- L2: [16,32]@[32,64], K=32 single step ----
        fx4 acc2[4] = {{0,0,0,0},{0,0,0,0},{0,0,0,0},{0,0,0,0}};
        {
            bfx8 a = *(const bfx8*)&sh1[ar*32 + ((quad ^ (ar & 3)) << 3)];
            #pragma unroll
            for (int j = 0; j < 4; ++j)
                acc2[j] = __builtin_amdgcn_mfma_f32_16x16x32_bf16(a, fw2[j], acc2[j], 0, 0, 0);
        }
        #pragma unroll
        for (int j = 0; j < 4; ++j)
            #pragma unroll
            for (int rg = 0; rg < 4; ++rg) {
                const int row = m0 + quad*4 + rg;
                const int col = j*16 + lr;
                const float v = fmaxf(acc2[j][rg] + rb2[j], 0.f);
                sh2[row*64 + (((col >> 3) ^ (row & 7)) << 3) + (col & 7)] = (__bf16)v;
            }

        // ---- L3: [16,64]@[64,128], two halves of 4 n-tiles (caps VGPR peak) ----
        #pragma unroll
        for (int h = 0; h < 2; ++h) {
            fx4 acc3[4] = {{0,0,0,0},{0,0,0,0},{0,0,0,0},{0,0,0,0}};
            #pragma unroll
            for (int ks = 0; ks < 2; ++ks) {
                bfx8 a = *(const bfx8*)&sh2[ar*64 + (((ks*4 + quad) ^ (ar & 7)) << 3)];
                #pragma unroll
                for (int j = 0; j < 4; ++j)
                    acc3[j] = __builtin_amdgcn_mfma_f32_16x16x32_bf16(a, fw3[h*4 + j][ks], acc3[j], 0, 0, 0);
            }
            #pragma unroll
            for (int j = 0; j < 4; ++j)
                #pragma unroll
                for (int rg = 0; rg < 4; ++rg) {
                    const int row = m0 + quad*4 + rg;
                    const int col = (h*4 + j)*16 + lr;
                    sy[row*SYS + col] = (__bf16)(acc3[j][rg] + rb3[h*4 + j]);
                }
        }
        __syncthreads();   // sy written by all waves, read by all below

        // ---- segment-run accumulation from sy (32 rows per group, serial) ----
        for (int rr = 0; rr < 32; ++rr) {
            const int r = grp*32 + rr;
            const int s = sseg[r];                     // LDS broadcast
            const float v = (float)sy[r*SYS + colA];   // 2-way conflict (free)
            if (s != cur_seg) {                        // uniform within group
                if (cur_seg >= 0) {
                    atomicAdd(&sums[(size_t)cur_seg * D_OUT + colA], run_sum);
                    if (colA == 0) atomicAdd(&counts[cur_seg], (float)run_len);
                }
                cur_seg = s; run_sum = 0.f; run_len = 0;
            }
            run_sum += v; run_len++;
        }
        __syncthreads();   // protect sy/sf overwrite next tile
    }

    if (cur_seg >= 0) {
        atomicAdd(&sums[(size_t)cur_seg * D_OUT + colA], run_sum);
        if (colA == 0) atomicAdd(&counts[cur_seg], (float)run_len);
    }
}

__global__ __launch_bounds__(256) void div_kernel(
    const float* __restrict__ sums, const float* __restrict__ counts,
    float* __restrict__ out, int total)
{
    const int i = blockIdx.x * 256 + threadIdx.x;
    if (i < total) out[i] = sums[i] / fmaxf(counts[i >> 7], 1.f);
}

extern "C" void kernel_launch(void* const* d_in, const int* in_sizes, int n_in,
                              void* d_out, int out_size, void* d_ws, size_t ws_size,
                              hipStream_t stream) {
    const float* f   = (const float*)d_in[0];
    const int*   seg = (const int*)  d_in[1];
    const float* W1 = (const float*)d_in[3];
    const float* b1 = (const float*)d_in[4];
    const float* W2 = (const float*)d_in[5];
    const float* b2 = (const float*)d_in[6];
    const float* W3 = (const float*)d_in[7];
    const float* b3 = (const float*)d_in[8];
    float* out = (float*)d_out;

    const int N = in_sizes[0] / D_IN;

    float* sums   = (float*)d_ws;                 // [NSEG * D_OUT]
    float* counts = sums + (size_t)NSEG * D_OUT;  // [NSEG]

    hipMemsetAsync(d_ws, 0, ((size_t)NSEG * D_OUT + NSEG) * sizeof(float), stream);

    const int ntiles  = (N + RT - 1) / RT;
    const int nblocks = (ntiles + TPB - 1) / TPB;
    mlp_seg_mfma<<<nblocks, BLOCK, 0, stream>>>(f, seg, W1, b1, W2, b2, W3, b3,
                                                sums, counts, N, ntiles);

    const int total = NSEG * D_OUT;
    div_kernel<<<(total + 255) / 256, 256, 0, stream>>>(sums, counts, out, total);
}